// Round 1
// baseline (254.140 us; speedup 1.0000x reference)
//
#include <hip/hip_runtime.h>

// TensorTrainGaussian: per-sample chain of 16x16 stochastic-matrix @ Gaussian-PDF
// products over M=32 steps, fully compute-bound (1.07e9 exp evaluations).
//
// Precompute (prep kernel, trivial cost):
//   P[b,a]     = -0.5*log2(e)/sigma^2
//   Q[b,a]     = -2*P*mu
//   Rc[m,b,a]  = P*mu^2 + log2( softmax_b(W[m,:,a]) / (sigma*sqrt(2*pi)) )
// Main kernel inner element: term = exp2( fma(P, x^2, fma(Q, x, Rc)) ),
//   acc[b] = fma(v[a], term, acc[b])  -> 3 VALU + 1 v_exp_f32 per element.

#define TT_N 131072
#define TT_M 32
#define TT_K 16

// ws layout (floats): z[16] | P[256] | Q[256] | Rbase[256] | Rc[8192]
#define WS_Z   0
#define WS_P   16
#define WS_Q   (16 + 256)
#define WS_RB  (16 + 512)
#define WS_RC  (16 + 768)

__global__ __launch_bounds__(512) void tt_prep(const float* __restrict__ Wk0,
                                               const float* __restrict__ W,
                                               const float* __restrict__ mu,
                                               const float* __restrict__ sigma,
                                               float* __restrict__ ws) {
    const int t = threadIdx.x;
    const float LOG2E = 1.4426950408889634f;

    float* z  = ws + WS_Z;
    float* P  = ws + WS_P;
    float* Q  = ws + WS_Q;
    float* Rb = ws + WS_RB;
    float* Rc = ws + WS_RC;

    if (t < 16) {
        // softmax over Wk0 (redundant per-thread, tiny)
        float mx = -1e30f;
        for (int i = 0; i < 16; ++i) mx = fmaxf(mx, Wk0[i]);
        float se = 0.f;
        for (int i = 0; i < 16; ++i) se += __expf(Wk0[i] - mx);
        z[t] = __expf(Wk0[t] - mx) / se;
    }
    if (t < 256) {
        float s     = sigma[t];
        float m_    = mu[t];
        float inv_s = 1.0f / s;
        float c2    = 0.72134752044448f * inv_s * inv_s;  // 0.5*log2(e)/sigma^2
        P[t] = -c2;
        Q[t] = 2.0f * c2 * m_;
        // log2(1/(sigma*sqrt(2pi))) - c2*mu^2
        Rb[t] = __log2f(inv_s * 0.3989422804014327f) - c2 * m_ * m_;
    }
    __syncthreads();

    // one thread per (m, a) column: softmax over b of W[m, b, a]
    const int m = t >> 4;
    const int a = t & 15;
    const float* Wc = W + m * 256 + a;  // stride 16 over b
    float mx = -1e30f;
    #pragma unroll
    for (int b = 0; b < 16; ++b) mx = fmaxf(mx, Wc[b * 16]);
    float se = 0.f;
    #pragma unroll
    for (int b = 0; b < 16; ++b) se += __expf(Wc[b * 16] - mx);
    float lse = __log2f(se);
    #pragma unroll
    for (int b = 0; b < 16; ++b) {
        float lw = (Wc[b * 16] - mx) * LOG2E - lse;  // log2(softmax weight)
        Rc[m * 256 + b * 16 + a] = Rb[b * 16 + a] + lw;
    }
}

__global__ __launch_bounds__(256) void tt_main(const float* __restrict__ X,
                                               const float* __restrict__ ws,
                                               float* __restrict__ out) {
    const int n = blockIdx.x * 256 + threadIdx.x;

    const float* z  = ws + WS_Z;
    const float* P  = ws + WS_P;
    const float* Q  = ws + WS_Q;
    const float* Rc = ws + WS_RC;

    float v[TT_K];
    #pragma unroll
    for (int a = 0; a < TT_K; ++a) v[a] = z[a];

    const float* xp = X + (size_t)n * TT_M;

    for (int m = 0; m < TT_M; ++m) {
        const float xm = xp[m];
        const float x2 = xm * xm;
        const float* R = Rc + m * 256;

        float acc[TT_K];
        #pragma unroll
        for (int b = 0; b < TT_K; ++b) {
            float s0 = 0.f;
            #pragma unroll
            for (int a = 0; a < TT_K; ++a) {
                const int i = b * 16 + a;
                float s = __fmaf_rn(P[i], x2, __fmaf_rn(Q[i], xm, R[i]));
                float e = __builtin_amdgcn_exp2f(s);
                s0 = __fmaf_rn(v[a], e, s0);
            }
            acc[b] = s0;
        }
        #pragma unroll
        for (int b = 0; b < TT_K; ++b) v[b] = acc[b];
    }

    float lik = 0.f;
    #pragma unroll
    for (int b = 0; b < TT_K; ++b) lik += v[b];

    // log(lik + eps), natural log via log2
    out[n] = __builtin_amdgcn_logf(lik + 2.2204460492503131e-16f) * 0.6931471805599453f;
}

extern "C" void kernel_launch(void* const* d_in, const int* in_sizes, int n_in,
                              void* d_out, int out_size, void* d_ws, size_t ws_size,
                              hipStream_t stream) {
    const float* X     = (const float*)d_in[0];
    const float* Wk0   = (const float*)d_in[1];
    const float* W     = (const float*)d_in[2];
    const float* mu    = (const float*)d_in[3];
    const float* sigma = (const float*)d_in[4];
    float* out = (float*)d_out;
    float* ws  = (float*)d_ws;

    tt_prep<<<1, 512, 0, stream>>>(Wk0, W, mu, sigma, ws);
    tt_main<<<TT_N / 256, 256, 0, stream>>>(X, ws, out);
}